// Round 1
// baseline (69.115 us; speedup 1.0000x reference)
//
#include <hip/hip_runtime.h>

#define Cc 8
#define Hh 128
#define Ww 128
#define Nn 64
#define Bb 8
#define Dd 169            // (C+2)*C + C + C*C + C + C + 1
#define HW (Hh * Ww)

__global__ __launch_bounds__(256, 2)
void seg_dice_main(const float* __restrict__ seg_feat,
                   const float* __restrict__ conv_weight,
                   const float* __restrict__ mask,
                   const int*   __restrict__ ind,
                   const float* __restrict__ target,
                   float* __restrict__ ws) {
    const int bn  = blockIdx.x;        // 0..511 = b*64 + n
    const int b   = bn >> 6;
    const int tid = threadIdx.x;

    __shared__ float w_s[Dd];
    const int ind_bn = ind[bn];

    // gather weight vector: conv_weight[b, d, ind]
    for (int i = tid; i < Dd; i += 256)
        w_s[i] = conv_weight[(size_t)b * Dd * HW + (size_t)i * HW + ind_bn];
    __syncthreads();

    // block-uniform weights -> registers (no per-pixel LDS reads)
    float w1r[8][10], b1r[8], w2r[8][8], b2r[8], w3r[8];
    #pragma unroll
    for (int o = 0; o < 8; ++o) {
        #pragma unroll
        for (int i = 0; i < 10; ++i) w1r[o][i] = w_s[o * 10 + i];
        b1r[o] = w_s[80 + o];
        #pragma unroll
        for (int i = 0; i < 8; ++i)  w2r[o][i] = w_s[88 + o * 8 + i];
        b2r[o] = w_s[152 + o];
        w3r[o] = w_s[160 + o];
    }
    const float b3r = w_s[168];

    const float m  = mask[bn];
    const float x0 = (float)(ind_bn & (Ww - 1));
    const float y0 = (float)(ind_bn >> 7);

    const float* seg_b  = seg_feat + (size_t)b * Cc * HW;
    const float* tgt_bn = target   + (size_t)bn * HW;

    float inter = 0.f, psum = 0.f, tsum = 0.f;

    #pragma unroll 1
    for (int p = tid; p < HW; p += 256) {
        float feat[8];
        #pragma unroll
        for (int c = 0; c < 8; ++c) feat[c] = seg_b[c * HW + p];
        const float xr = ((float)(p & (Ww - 1)) - x0) * (1.0f / 128.0f);
        const float yr = ((float)(p >> 7)       - y0) * (1.0f / 128.0f);

        float h1[8];
        #pragma unroll
        for (int o = 0; o < 8; ++o) {
            float a = b1r[o];
            #pragma unroll
            for (int c = 0; c < 8; ++c) a = fmaf(w1r[o][c], feat[c], a);
            a = fmaf(w1r[o][8], xr, a);
            a = fmaf(w1r[o][9], yr, a);
            h1[o] = fmaxf(a, 0.f);
        }
        float h2[8];
        #pragma unroll
        for (int o = 0; o < 8; ++o) {
            float a = b2r[o];
            #pragma unroll
            for (int c = 0; c < 8; ++c) a = fmaf(w2r[o][c], h1[c], a);
            h2[o] = fmaxf(a, 0.f);
        }
        float z = b3r;
        #pragma unroll
        for (int c = 0; c < 8; ++c) z = fmaf(w3r[c], h2[c], z);

        const float out  = 1.0f / (1.0f + __expf(-z));
        const float pred = out * m;
        const float tgt  = tgt_bn[p] * m;
        inter = fmaf(pred, tgt, inter);
        psum  = fmaf(pred, pred, psum);
        tsum  = fmaf(tgt,  tgt,  tsum);
    }

    // wave reduce (64-lane) then cross-wave via LDS
    #pragma unroll
    for (int off = 32; off > 0; off >>= 1) {
        inter += __shfl_down(inter, off);
        psum  += __shfl_down(psum,  off);
        tsum  += __shfl_down(tsum,  off);
    }
    __shared__ float red[3][4];
    const int wave = tid >> 6;
    if ((tid & 63) == 0) { red[0][wave] = inter; red[1][wave] = psum; red[2][wave] = tsum; }
    __syncthreads();
    if (tid == 0) {
        const float i2 = red[0][0] + red[0][1] + red[0][2] + red[0][3];
        const float p2 = red[1][0] + red[1][1] + red[1][2] + red[1][3];
        const float t2 = red[2][0] + red[2][1] + red[2][2] + red[2][3];
        atomicAdd(&ws[b * 3 + 0], i2);
        atomicAdd(&ws[b * 3 + 1], p2);
        atomicAdd(&ws[b * 3 + 2], t2);
    }
}

__global__ void seg_dice_final(const float* __restrict__ ws, float* __restrict__ out) {
    if (threadIdx.x == 0) {
        float acc = 0.f;
        #pragma unroll
        for (int b = 0; b < Bb; ++b) {
            const float inter = ws[b * 3 + 0];
            const float p     = ws[b * 3 + 1];
            const float t     = ws[b * 3 + 2];
            acc += 1.0f - (2.0f * inter + 1.0f) / (p + t + 1.0f);
        }
        out[0] = acc * (1.0f / (float)Bb);
    }
}

extern "C" void kernel_launch(void* const* d_in, const int* in_sizes, int n_in,
                              void* d_out, int out_size, void* d_ws, size_t ws_size,
                              hipStream_t stream) {
    const float* seg_feat    = (const float*)d_in[0];
    const float* conv_weight = (const float*)d_in[1];
    const float* mask        = (const float*)d_in[2];
    const int*   ind         = (const int*)d_in[3];
    const float* target      = (const float*)d_in[4];
    float* out = (float*)d_out;
    float* ws  = (float*)d_ws;

    // zero the 8x3 partial accumulators
    hipMemsetAsync(ws, 0, Bb * 3 * sizeof(float), stream);

    seg_dice_main<<<Bb * Nn, 256, 0, stream>>>(seg_feat, conv_weight, mask, ind, target, ws);
    seg_dice_final<<<1, 64, 0, stream>>>(ws, out);
}